// Round 10
// baseline (537.529 us; speedup 1.0000x reference)
//
#include <hip/hip_runtime.h>
#include <hip/hip_bf16.h>
#include <hip/hip_fp16.h>
#include <math.h>

// Problem constants
#define DD   1024
#define EE   8
#define HH   512
#define NTOK 16384        // B*T
#define MAXMT 40          // max 128-row tiles per expert (n_e ~ 4096, sigma ~60 -> 5120 >>safe)
#define NSL_D 4           // down: N=512  -> 4 slices of 128
#define NSL_U 8           // up:   N=1024 -> 8 slices of 128
#define NWD  (EE * MAXMT * NSL_D)   // 1280 blocks, %8==0
#define NWU  (EE * MAXMT * NSL_U)   // 2560 blocks, %8==0

typedef __attribute__((ext_vector_type(8))) short short8;   // 8 bf16
typedef __attribute__((ext_vector_type(4))) float floatx4;  // MFMA C/D frag

__device__ __forceinline__ ushort f2bfu(float f) {
    __hip_bfloat16 h = __float2bfloat16(f);   // RNE
    return *reinterpret_cast<ushort*>(&h);
}
__device__ __forceinline__ float bfu2f(ushort u) {
    union { unsigned u; float f; } cv; cv.u = ((unsigned)u) << 16; return cv.f;
}

// async global->LDS, 16B per lane. LDS dest = wave-uniform base + lane*16.
__device__ __forceinline__ void glds16(const void* g, void* l) {
    __builtin_amdgcn_global_load_lds(
        (const __attribute__((address_space(1))) unsigned int*)g,
        (__attribute__((address_space(3))) unsigned int*)l, 16, 0, 0);
}

// ---------------------------------------------------------------------------
// Kernel 1: BOTH weight transposes in one launch (one fewer grid-drain bubble).
// z<8: Wd [D][H] -> WdT [H][D] (expert z); z>=8: Wu [H][D] -> WuT [D][H].
// Block (0,0,0) also zeroes the 256-int counter region.
// ---------------------------------------------------------------------------
__global__ __launch_bounds__(256) void trans2_k(
    const float* __restrict__ Wd, ushort* __restrict__ WdT,
    const float* __restrict__ Wu, ushort* __restrict__ WuT,
    int* __restrict__ cnt)
{
    if (blockIdx.x == 0 && blockIdx.y == 0 && blockIdx.z == 0 && threadIdx.x < 256)
        cnt[threadIdx.x] = 0;
    const int z = blockIdx.z;
    const float* src; ushort* dst; int R, C, e;
    if (z < EE) { src = Wd; dst = WdT; R = DD; C = HH; e = z; }
    else        { src = Wu; dst = WuT; R = HH; C = DD; e = z - EE; }
    if ((int)blockIdx.x >= C / 64 || (int)blockIdx.y >= R / 64) return;
    const int r0 = blockIdx.y * 64, c0 = blockIdx.x * 64;
    __shared__ float t[64][65];
    const int tid = threadIdx.x;
    const int cseg = (tid & 15) * 4, rr = tid >> 4;
#pragma unroll
    for (int j = 0; j < 4; ++j) {
        const int r = rr + j * 16;
        const float4 v = *(const float4*)(src + ((size_t)e * R + r0 + r) * C + c0 + cseg);
        t[r][cseg] = v.x; t[r][cseg+1] = v.y; t[r][cseg+2] = v.z; t[r][cseg+3] = v.w;
    }
    __syncthreads();
    const int rseg = (tid & 15) * 4;
#pragma unroll
    for (int j = 0; j < 4; ++j) {
        const int crow = (tid >> 4) + j * 16;
        ushort o[4];
#pragma unroll
        for (int q = 0; q < 4; ++q) o[q] = f2bfu(t[rseg + q][crow]);
        *(uint2*)(dst + ((size_t)e * C + c0 + crow) * R + r0 + rseg) = *(uint2*)o;
    }
}

// ---------------------------------------------------------------------------
// Kernel 2: router + x->bf16 cvt (unchanged from round 7 — LDS weight stage +
// per-block LDS-aggregated atomics, 1 atomicAdd per expert per block;
// router dropped out of top-5 with this structure).
// entry payload = tok | slot<<14 | gate_f16<<16.
// ---------------------------------------------------------------------------
__device__ __forceinline__ void route_token(
    const float* ar, const float* an, int t,
    const float* __restrict__ br, const float* __restrict__ bn,
    const float* __restrict__ noise,
    unsigned& e0, unsigned& p0, unsigned& e1, unsigned& p1)
{
    float noisy[EE];
#pragma unroll
    for (int e = 0; e < EE; ++e) {
        const float lg = ar[e] + br[e];
        const float nl = an[e] + bn[e];
        const float sp = fmaxf(nl, 0.f) + log1pf(expf(-fabsf(nl)));
        noisy[e] = lg + noise[(size_t)t * EE + e] * sp;
    }
    int i0 = 0;
#pragma unroll
    for (int e = 1; e < EE; ++e) if (noisy[e] > noisy[i0]) i0 = e;
    int i1 = (i0 == 0) ? 1 : 0;
#pragma unroll
    for (int e = 0; e < EE; ++e) if (e != i0 && noisy[e] > noisy[i1]) i1 = e;
    const float ex = expf(noisy[i1] - noisy[i0]);
    const float g0 = 1.f / (1.f + ex);
    const float g1 = ex / (1.f + ex);
    __half h0 = __float2half_rn(g0), h1 = __float2half_rn(g1);
    e0 = (unsigned)i0;
    e1 = (unsigned)i1;
    p0 = (unsigned)t | ((unsigned)*reinterpret_cast<ushort*>(&h0) << 16);
    p1 = (unsigned)t | (1u << 14) | ((unsigned)*reinterpret_cast<ushort*>(&h1) << 16);
}

__global__ __launch_bounds__(512) void router_k(
    const float* __restrict__ x, const float* __restrict__ Wr, const float* __restrict__ br,
    const float* __restrict__ Wn, const float* __restrict__ bn, const float* __restrict__ noise,
    int* __restrict__ cnt, unsigned* __restrict__ entries, ushort* __restrict__ xb)
{
    __shared__ __align__(16) float WT[DD * 20];   // 80 KB; head reused as agg buffer at the tail

    const int tid = threadIdx.x;
    {
        const int d0 = tid * 2;
#pragma unroll
        for (int r = 0; r < 2; ++r) {
            const int d = d0 + r;
            float4 a = *(const float4*)(Wr + (size_t)d * EE);
            float4 b = *(const float4*)(Wr + (size_t)d * EE + 4);
            float4 c = *(const float4*)(Wn + (size_t)d * EE);
            float4 e4 = *(const float4*)(Wn + (size_t)d * EE + 4);
            float* row = &WT[d * 20];
            *(float4*)(row + 0)  = a;
            *(float4*)(row + 4)  = b;
            *(float4*)(row + 8)  = c;
            *(float4*)(row + 12) = e4;
        }
    }
    __syncthreads();

    const int wave = tid >> 6;
    const int lane = tid & 63;
    const int t0 = blockIdx.x * 16 + wave * 2;

    float a0r[EE], a0n[EE], a1r[EE], a1n[EE];
#pragma unroll
    for (int e = 0; e < EE; ++e) { a0r[e] = 0.f; a0n[e] = 0.f; a1r[e] = 0.f; a1n[e] = 0.f; }

    const float* xr0 = x + (size_t)t0 * DD;
    const float* xr1 = xr0 + DD;
    ushort* xb0 = xb + (size_t)t0 * DD;
    ushort* xb1 = xb0 + DD;

#pragma unroll 4
    for (int s = 0; s < DD / 64; ++s) {
        const int d = s * 64 + lane;
        const float x0 = xr0[d];
        const float x1 = xr1[d];
        xb0[d] = f2bfu(x0);
        xb1[d] = f2bfu(x1);
        const float* row = &WT[d * 20];
        const float4 w0 = *(const float4*)(row + 0);
        const float4 w1 = *(const float4*)(row + 4);
        const float4 w2 = *(const float4*)(row + 8);
        const float4 w3 = *(const float4*)(row + 12);
        const float wr[8] = { w0.x, w0.y, w0.z, w0.w, w1.x, w1.y, w1.z, w1.w };
        const float wn[8] = { w2.x, w2.y, w2.z, w2.w, w3.x, w3.y, w3.z, w3.w };
#pragma unroll
        for (int e = 0; e < EE; ++e) {
            a0r[e] = fmaf(x0, wr[e], a0r[e]);
            a0n[e] = fmaf(x0, wn[e], a0n[e]);
            a1r[e] = fmaf(x1, wr[e], a1r[e]);
            a1n[e] = fmaf(x1, wn[e], a1n[e]);
        }
    }
#pragma unroll
    for (int off = 32; off > 0; off >>= 1) {
#pragma unroll
        for (int e = 0; e < EE; ++e) {
            a0r[e] += __shfl_xor(a0r[e], off);
            a0n[e] += __shfl_xor(a0n[e], off);
            a1r[e] += __shfl_xor(a1r[e], off);
            a1n[e] += __shfl_xor(a1n[e], off);
        }
    }

    unsigned e0a, p0a, e1a, p1a, e0b, p0b, e1b, p1b;
    if (lane == 0) {
        route_token(a0r, a0n, t0,     br, bn, noise, e0a, p0a, e1a, p1a);
        route_token(a1r, a1n, t0 + 1, br, bn, noise, e0b, p0b, e1b, p1b);
    }

    __syncthreads();    // all waves done reading WT -> safe to alias
    unsigned* aggp = (unsigned*)WT;        // [32] payloads
    unsigned* agge = aggp + 32;            // [32] expert ids
    if (lane == 0) {
        const int b = wave * 4;
        aggp[b + 0] = p0a; agge[b + 0] = e0a;
        aggp[b + 1] = p1a; agge[b + 1] = e1a;
        aggp[b + 2] = p0b; agge[b + 2] = e0b;
        aggp[b + 3] = p1b; agge[b + 3] = e1b;
    }
    __syncthreads();
    if (tid < EE) {
        int c = 0;
#pragma unroll
        for (int j = 0; j < 32; ++j) c += (agge[j] == (unsigned)tid);
        if (c) {
            int base = atomicAdd(&cnt[tid * 16], c);
            for (int j = 0; j < 32; ++j)
                if (agge[j] == (unsigned)tid) entries[tid * NTOK + (base++)] = aggp[j];
        }
    }
}

// ---------------------------------------------------------------------------
// Grouped GEMM: round-7 measured-best structure (down 103 us):
// 128x128x64 tile, 4 waves (2x2), XOR-swizzled LDS (0 bank conflicts all
// rounds), counted-vmcnt double-buffer, setprio around MFMA, bijective
// chunked XCD swizzle (expert-per-XCD; FETCH ~= compulsory, verified R7).
// Round-8 lesson: 256^2 at 2-phase regressed (1 block/CU lost cross-block
// overlap; 4 MB/XCD hid working set thrashed the XCD L2 -> WRITE 2x).
// ---------------------------------------------------------------------------

// Kernel 4: down: hid[off+row][n] = gelu(x_gathered @ WdT^T + bd)
__global__ __launch_bounds__(256) void down_k(
    const ushort* __restrict__ xb, const ushort* __restrict__ WdT, const float* __restrict__ bd,
    const int* __restrict__ cnt, const unsigned* __restrict__ entries, ushort* __restrict__ hid)
{
    const int bx = blockIdx.x;
    const int wid = (bx & 7) * (NWD >> 3) + (bx >> 3);
    const int n0 = (wid % NSL_D) * 128;
    const int tile = wid / NSL_D;
    const int tm = tile % MAXMT;
    const int g = tile / MAXMT, e = g;
    const int n_g = cnt[g * 16];
    if (tm * 128 >= n_g) return;

    int og = 0;
    for (int gg = 0; gg < g; ++gg) og += cnt[gg * 16];   // exclusive prefix

    __shared__ __align__(16) ushort As[2 * 128 * 64];
    __shared__ __align__(16) ushort Bs[2 * 128 * 64];
    __shared__ unsigned ecache[128];

    const int tid = threadIdx.x, lane = tid & 63, w = tid >> 6;
    const int wm = w >> 1, wn = w & 1;
    const int fr = lane & 15, fq = lane >> 4;

    if (tid < 128) {
        const int ridx = min(tm * 128 + tid, n_g - 1);
        ecache[tid] = entries[g * NTOK + ridx];
    }
    __syncthreads();

    const int lr = lane >> 3, seg = lane & 7;
    const int slog = seg ^ lr;                 // row&7 == lr for all j
    const ushort* gA[4]; const ushort* gB[4];
    int loff[4];
    const ushort* WTe = WdT + (size_t)e * HH * DD;
#pragma unroll
    for (int j = 0; j < 4; ++j) {
        const int row = w * 32 + j * 8 + lr;
        const int tok = (int)(ecache[row] & 0x3FFFu);
        gA[j] = xb + (size_t)tok * DD + slog * 8;
        gB[j] = WTe + (size_t)(n0 + row) * DD + slog * 8;
        loff[j] = (w * 256 + j * 64) * 16;     // byte offset within one buffer
    }

    floatx4 acc[4][4];
#pragma unroll
    for (int i = 0; i < 4; ++i)
#pragma unroll
        for (int j = 0; j < 4; ++j) acc[i][j] = (floatx4){0.f, 0.f, 0.f, 0.f};

    const int axr = wm * 64 + fr;
    const int bxr = wn * 64 + fr;

    // prologue: tile 0 -> buf 0 (8 glds per wave in flight)
#pragma unroll
    for (int j = 0; j < 4; ++j) {
        glds16(gA[j], (char*)As + loff[j]);
        glds16(gB[j], (char*)Bs + loff[j]);
    }

    int cur = 0;
    for (int k0 = 0; k0 < DD; k0 += 64) {
        if (k0 + 64 < DD) {
            const int nb = (cur ^ 1) * 16384;
#pragma unroll
            for (int j = 0; j < 4; ++j) {
                glds16(gA[j] + k0 + 64, (char*)As + nb + loff[j]);
                glds16(gB[j] + k0 + 64, (char*)Bs + nb + loff[j]);
            }
            asm volatile("s_waitcnt vmcnt(8)" ::: "memory");  // retire tile-t only
        } else {
            asm volatile("s_waitcnt vmcnt(0)" ::: "memory");  // last tile: drain
        }
        __builtin_amdgcn_sched_barrier(0);
        __builtin_amdgcn_s_barrier();          // all waves: tile-t fully in LDS
        asm volatile("" ::: "memory");
        const int cb = cur * 8192;
        __builtin_amdgcn_s_setprio(1);
#pragma unroll
        for (int kh = 0; kh < 2; ++kh) {
            short8 a[4], b[4];
#pragma unroll
            for (int mt = 0; mt < 4; ++mt) {
                const int r = axr + mt * 16;
                a[mt] = *(const short8*)&As[cb + r * 64 + ((kh * 4 + fq) ^ (r & 7)) * 8];
            }
#pragma unroll
            for (int nt = 0; nt < 4; ++nt) {
                const int r = bxr + nt * 16;
                b[nt] = *(const short8*)&Bs[cb + r * 64 + ((kh * 4 + fq) ^ (r & 7)) * 8];
            }
#pragma unroll
            for (int mt = 0; mt < 4; ++mt)
#pragma unroll
                for (int nt = 0; nt < 4; ++nt)
                    acc[mt][nt] = __builtin_amdgcn_mfma_f32_16x16x32_bf16(a[mt], b[nt], acc[mt][nt], 0, 0, 0);
        }
        __builtin_amdgcn_s_setprio(0);
        asm volatile("" ::: "memory");
        __builtin_amdgcn_s_barrier();          // reads of buf[cur] done before overwrite
        cur ^= 1;
    }

    const int hbase = og + tm * 128;
#pragma unroll
    for (int nt = 0; nt < 4; ++nt) {
        const int n = n0 + wn * 64 + nt * 16 + fr;
        const float bias = bd[e * HH + n];
#pragma unroll
        for (int mt = 0; mt < 4; ++mt)
#pragma unroll
            for (int i = 0; i < 4; ++i) {
                const int rl = wm * 64 + mt * 16 + fq * 4 + i;
                if (tm * 128 + rl < n_g) {
                    const float v = acc[mt][nt][i] + bias;
                    const float ge = 0.5f * v * (1.f + erff(v * 0.7071067811865475f));
                    hid[(size_t)(hbase + rl) * HH + n] = f2bfu(ge);
                }
            }
    }
}

// Kernel 5: up: out[tok][n] += (hid @ WuT^T + bu) * gate   (fp32 atomicAdd).
// slots + combine ELIMINATED: each out element receives exactly 2
// contributions (top1 + top2 expert blocks); 2-operand fp32 add is
// order-independent -> deterministic. out zeroed via hipMemsetAsync.
__global__ __launch_bounds__(256) void up_k(
    const ushort* __restrict__ hid, const ushort* __restrict__ WuT, const float* __restrict__ bu,
    const int* __restrict__ cnt, const unsigned* __restrict__ entries, float* __restrict__ out)
{
    const int bx = blockIdx.x;
    const int wid = (bx & 7) * (NWU >> 3) + (bx >> 3);
    const int n0 = (wid % NSL_U) * 128;
    const int tile = wid / NSL_U;
    const int tm = tile % MAXMT;
    const int g = tile / MAXMT, e = g;
    const int n_g = cnt[g * 16];
    if (tm * 128 >= n_g) return;

    int hbase = 0;
    for (int gg = 0; gg < g; ++gg) hbase += cnt[gg * 16];  // exclusive prefix

    __shared__ __align__(16) ushort As[2 * 128 * 64];
    __shared__ __align__(16) ushort Bs[2 * 128 * 64];
    __shared__ unsigned ecache[128];

    const int tid = threadIdx.x, lane = tid & 63, w = tid >> 6;
    const int wm = w >> 1, wn = w & 1;
    const int fr = lane & 15, fq = lane >> 4;

    if (tid < 128) {
        const int ridx = min(tm * 128 + tid, n_g - 1);
        ecache[tid] = entries[g * NTOK + ridx];
    }
    __syncthreads();

    const int lr = lane >> 3, seg = lane & 7;
    const int slog = seg ^ lr;
    const ushort* gA[4]; const ushort* gB[4];
    int loff[4];
    const ushort* WTe = WuT + (size_t)e * DD * HH;
#pragma unroll
    for (int j = 0; j < 4; ++j) {
        const int row = w * 32 + j * 8 + lr;
        const int ar = min(tm * 128 + row, n_g - 1);
        gA[j] = hid + (size_t)(hbase + ar) * HH + slog * 8;
        gB[j] = WTe + (size_t)(n0 + row) * HH + slog * 8;
        loff[j] = (w * 256 + j * 64) * 16;
    }

    floatx4 acc[4][4];
#pragma unroll
    for (int i = 0; i < 4; ++i)
#pragma unroll
        for (int j = 0; j < 4; ++j) acc[i][j] = (floatx4){0.f, 0.f, 0.f, 0.f};

    const int axr = wm * 64 + fr;
    const int bxr = wn * 64 + fr;

    // prologue: tile 0 -> buf 0
#pragma unroll
    for (int j = 0; j < 4; ++j) {
        glds16(gA[j], (char*)As + loff[j]);
        glds16(gB[j], (char*)Bs + loff[j]);
    }

    int cur = 0;
    for (int k0 = 0; k0 < HH; k0 += 64) {
        if (k0 + 64 < HH) {
            const int nb = (cur ^ 1) * 16384;
#pragma unroll
            for (int j = 0; j < 4; ++j) {
                glds16(gA[j] + k0 + 64, (char*)As + nb + loff[j]);
                glds16(gB[j] + k0 + 64, (char*)Bs + nb + loff[j]);
            }
            asm volatile("s_waitcnt vmcnt(8)" ::: "memory");
        } else {
            asm volatile("s_waitcnt vmcnt(0)" ::: "memory");
        }
        __builtin_amdgcn_sched_barrier(0);
        __builtin_amdgcn_s_barrier();
        asm volatile("" ::: "memory");
        const int cb = cur * 8192;
        __builtin_amdgcn_s_setprio(1);
#pragma unroll
        for (int kh = 0; kh < 2; ++kh) {
            short8 a[4], b[4];
#pragma unroll
            for (int mt = 0; mt < 4; ++mt) {
                const int r = axr + mt * 16;
                a[mt] = *(const short8*)&As[cb + r * 64 + ((kh * 4 + fq) ^ (r & 7)) * 8];
            }
#pragma unroll
            for (int nt = 0; nt < 4; ++nt) {
                const int r = bxr + nt * 16;
                b[nt] = *(const short8*)&Bs[cb + r * 64 + ((kh * 4 + fq) ^ (r & 7)) * 8];
            }
#pragma unroll
            for (int mt = 0; mt < 4; ++mt)
#pragma unroll
                for (int nt = 0; nt < 4; ++nt)
                    acc[mt][nt] = __builtin_amdgcn_mfma_f32_16x16x32_bf16(a[mt], b[nt], acc[mt][nt], 0, 0, 0);
        }
        __builtin_amdgcn_s_setprio(0);
        asm volatile("" ::: "memory");
        __builtin_amdgcn_s_barrier();
        cur ^= 1;
    }

#pragma unroll
    for (int nt = 0; nt < 4; ++nt) {
        const int n = n0 + wn * 64 + nt * 16 + fr;
        const float bias = bu[e * DD + n];
#pragma unroll
        for (int mt = 0; mt < 4; ++mt)
#pragma unroll
            for (int i = 0; i < 4; ++i) {
                const int rl = wm * 64 + mt * 16 + fq * 4 + i;
                if (tm * 128 + rl < n_g) {
                    const unsigned en = ecache[rl];
                    const int tok = (int)(en & 0x3FFFu);
                    ushort hb = (ushort)(en >> 16);
                    const float gate = __half2float(*reinterpret_cast<__half*>(&hb));
                    atomicAdd(out + (size_t)tok * DD + n, (acc[mt][nt][i] + bias) * gate);
                }
            }
    }
}

// ---------------------------------------------------------------------------
// Workspace layout (bytes):
//   0         cnt    : int[8] @ 64B stride (256-int region zeroed by trans2_k)
//   2048      entries: u32[8][16384]             (0.5 MB)
//   1050624   xb     : bf16 [16384][1024]        (32 MB)
//   34605056  WdT    : bf16 [8][512 h][1024 d]   (8 MB)
//   42993664  WuT    : bf16 [8][1024 d][512 h]   (8 MB)
//   51382272  hid    : bf16 [32768][512]         (32 MB)
//   (slots eliminated — up_k accumulates fp32 directly into d_out)
// ---------------------------------------------------------------------------
extern "C" void kernel_launch(void* const* d_in, const int* in_sizes, int n_in,
                              void* d_out, int out_size, void* d_ws, size_t ws_size,
                              hipStream_t stream)
{
    const float* x     = (const float*)d_in[0];
    const float* Wr    = (const float*)d_in[1];
    const float* br    = (const float*)d_in[2];
    const float* Wn    = (const float*)d_in[3];
    const float* bn    = (const float*)d_in[4];
    const float* Wd    = (const float*)d_in[5];
    const float* bd    = (const float*)d_in[6];
    const float* Wu    = (const float*)d_in[7];
    const float* bu    = (const float*)d_in[8];
    const float* noise = (const float*)d_in[9];

    char* ws = (char*)d_ws;
    int*      cnt     = (int*)(ws + 0);
    unsigned* entries = (unsigned*)(ws + 2048);
    ushort*   xb      = (ushort*)(ws + 1050624);
    ushort*   WdT     = (ushort*)(ws + 34605056);
    ushort*   WuT     = (ushort*)(ws + 42993664);
    ushort*   hid     = (ushort*)(ws + 51382272);

    hipMemsetAsync(d_out, 0, out_size, stream);   // out accumulator (graph-capturable stream op)
    trans2_k<<<dim3(16, 16, 16), 256, 0, stream>>>(Wd, WdT, Wu, WuT, cnt);
    router_k<<<NTOK / 16, 512, 0, stream>>>(x, Wr, br, Wn, bn, noise, cnt, entries, xb);
    down_k<<<NWD, 256, 0, stream>>>(xb, WdT, bd, cnt, entries, hid);
    up_k<<<NWU, 256, 0, stream>>>(hid, WuT, bu, cnt, entries, (float*)d_out);
}

// Round 13
// 462.757 us; speedup vs baseline: 1.1616x; 1.1616x over previous
//
#include <hip/hip_runtime.h>
#include <hip/hip_bf16.h>
#include <hip/hip_fp16.h>
#include <math.h>

// Problem constants
#define DD   1024
#define EE   8
#define HH   512
#define NTOK 16384        // B*T
#define MAXMT 40          // max 128-row tiles per expert (n_e ~ 4096, sigma ~60 -> 5120 >>safe)
#define NSL_D 4           // down: N=512  -> 4 slices of 128
#define NSL_U 8           // up:   N=1024 -> 8 slices of 128
#define NWD  (EE * MAXMT * NSL_D)   // 1280 blocks, %8==0
#define NWU  (EE * MAXMT * NSL_U)   // 2560 blocks, %8==0

typedef __attribute__((ext_vector_type(8))) short short8;   // 8 bf16
typedef __attribute__((ext_vector_type(4))) float floatx4;  // MFMA C/D frag

__device__ __forceinline__ ushort f2bfu(float f) {
    __hip_bfloat16 h = __float2bfloat16(f);   // RNE
    return *reinterpret_cast<ushort*>(&h);
}
__device__ __forceinline__ float bfu2f(ushort u) {
    union { unsigned u; float f; } cv; cv.u = ((unsigned)u) << 16; return cv.f;
}

// async global->LDS, 16B per lane. LDS dest = wave-uniform base + lane*16.
__device__ __forceinline__ void glds16(const void* g, void* l) {
    __builtin_amdgcn_global_load_lds(
        (const __attribute__((address_space(1))) unsigned int*)g,
        (__attribute__((address_space(3))) unsigned int*)l, 16, 0, 0);
}

// ---------------------------------------------------------------------------
// Kernel 1: BOTH weight transposes in one launch (one fewer grid-drain bubble).
// z<8: Wd [D][H] -> WdT [H][D] (expert z); z>=8: Wu [H][D] -> WuT [D][H].
// Block (0,0,0) also zeroes the 256-int counter region.
// ---------------------------------------------------------------------------
__global__ __launch_bounds__(256) void trans2_k(
    const float* __restrict__ Wd, ushort* __restrict__ WdT,
    const float* __restrict__ Wu, ushort* __restrict__ WuT,
    int* __restrict__ cnt)
{
    if (blockIdx.x == 0 && blockIdx.y == 0 && blockIdx.z == 0 && threadIdx.x < 256)
        cnt[threadIdx.x] = 0;
    const int z = blockIdx.z;
    const float* src; ushort* dst; int R, C, e;
    if (z < EE) { src = Wd; dst = WdT; R = DD; C = HH; e = z; }
    else        { src = Wu; dst = WuT; R = HH; C = DD; e = z - EE; }
    if ((int)blockIdx.x >= C / 64 || (int)blockIdx.y >= R / 64) return;
    const int r0 = blockIdx.y * 64, c0 = blockIdx.x * 64;
    __shared__ float t[64][65];
    const int tid = threadIdx.x;
    const int cseg = (tid & 15) * 4, rr = tid >> 4;
#pragma unroll
    for (int j = 0; j < 4; ++j) {
        const int r = rr + j * 16;
        const float4 v = *(const float4*)(src + ((size_t)e * R + r0 + r) * C + c0 + cseg);
        t[r][cseg] = v.x; t[r][cseg+1] = v.y; t[r][cseg+2] = v.z; t[r][cseg+3] = v.w;
    }
    __syncthreads();
    const int rseg = (tid & 15) * 4;
#pragma unroll
    for (int j = 0; j < 4; ++j) {
        const int crow = (tid >> 4) + j * 16;
        ushort o[4];
#pragma unroll
        for (int q = 0; q < 4; ++q) o[q] = f2bfu(t[rseg + q][crow]);
        *(uint2*)(dst + ((size_t)e * C + c0 + crow) * R + r0 + rseg) = *(uint2*)o;
    }
}

// ---------------------------------------------------------------------------
// Kernel 2: router + x->bf16 cvt (round-7 structure — LDS weight stage +
// per-block LDS-aggregated atomics, 1 atomicAdd per expert per block;
// router dropped out of top-5 with this structure).
// entry payload = tok | slot<<14 | gate_f16<<16.
// ---------------------------------------------------------------------------
__device__ __forceinline__ void route_token(
    const float* ar, const float* an, int t,
    const float* __restrict__ br, const float* __restrict__ bn,
    const float* __restrict__ noise,
    unsigned& e0, unsigned& p0, unsigned& e1, unsigned& p1)
{
    float noisy[EE];
#pragma unroll
    for (int e = 0; e < EE; ++e) {
        const float lg = ar[e] + br[e];
        const float nl = an[e] + bn[e];
        const float sp = fmaxf(nl, 0.f) + log1pf(expf(-fabsf(nl)));
        noisy[e] = lg + noise[(size_t)t * EE + e] * sp;
    }
    int i0 = 0;
#pragma unroll
    for (int e = 1; e < EE; ++e) if (noisy[e] > noisy[i0]) i0 = e;
    int i1 = (i0 == 0) ? 1 : 0;
#pragma unroll
    for (int e = 0; e < EE; ++e) if (e != i0 && noisy[e] > noisy[i1]) i1 = e;
    const float ex = expf(noisy[i1] - noisy[i0]);
    const float g0 = 1.f / (1.f + ex);
    const float g1 = ex / (1.f + ex);
    __half h0 = __float2half_rn(g0), h1 = __float2half_rn(g1);
    e0 = (unsigned)i0;
    e1 = (unsigned)i1;
    p0 = (unsigned)t | ((unsigned)*reinterpret_cast<ushort*>(&h0) << 16);
    p1 = (unsigned)t | (1u << 14) | ((unsigned)*reinterpret_cast<ushort*>(&h1) << 16);
}

__global__ __launch_bounds__(512) void router_k(
    const float* __restrict__ x, const float* __restrict__ Wr, const float* __restrict__ br,
    const float* __restrict__ Wn, const float* __restrict__ bn, const float* __restrict__ noise,
    int* __restrict__ cnt, unsigned* __restrict__ entries, ushort* __restrict__ xb)
{
    __shared__ __align__(16) float WT[DD * 20];   // 80 KB; head reused as agg buffer at the tail

    const int tid = threadIdx.x;
    {
        const int d0 = tid * 2;
#pragma unroll
        for (int r = 0; r < 2; ++r) {
            const int d = d0 + r;
            float4 a = *(const float4*)(Wr + (size_t)d * EE);
            float4 b = *(const float4*)(Wr + (size_t)d * EE + 4);
            float4 c = *(const float4*)(Wn + (size_t)d * EE);
            float4 e4 = *(const float4*)(Wn + (size_t)d * EE + 4);
            float* row = &WT[d * 20];
            *(float4*)(row + 0)  = a;
            *(float4*)(row + 4)  = b;
            *(float4*)(row + 8)  = c;
            *(float4*)(row + 12) = e4;
        }
    }
    __syncthreads();

    const int wave = tid >> 6;
    const int lane = tid & 63;
    const int t0 = blockIdx.x * 16 + wave * 2;

    float a0r[EE], a0n[EE], a1r[EE], a1n[EE];
#pragma unroll
    for (int e = 0; e < EE; ++e) { a0r[e] = 0.f; a0n[e] = 0.f; a1r[e] = 0.f; a1n[e] = 0.f; }

    const float* xr0 = x + (size_t)t0 * DD;
    const float* xr1 = xr0 + DD;
    ushort* xb0 = xb + (size_t)t0 * DD;
    ushort* xb1 = xb0 + DD;

#pragma unroll 4
    for (int s = 0; s < DD / 64; ++s) {
        const int d = s * 64 + lane;
        const float x0 = xr0[d];
        const float x1 = xr1[d];
        xb0[d] = f2bfu(x0);
        xb1[d] = f2bfu(x1);
        const float* row = &WT[d * 20];
        const float4 w0 = *(const float4*)(row + 0);
        const float4 w1 = *(const float4*)(row + 4);
        const float4 w2 = *(const float4*)(row + 8);
        const float4 w3 = *(const float4*)(row + 12);
        const float wr[8] = { w0.x, w0.y, w0.z, w0.w, w1.x, w1.y, w1.z, w1.w };
        const float wn[8] = { w2.x, w2.y, w2.z, w2.w, w3.x, w3.y, w3.z, w3.w };
#pragma unroll
        for (int e = 0; e < EE; ++e) {
            a0r[e] = fmaf(x0, wr[e], a0r[e]);
            a0n[e] = fmaf(x0, wn[e], a0n[e]);
            a1r[e] = fmaf(x1, wr[e], a1r[e]);
            a1n[e] = fmaf(x1, wn[e], a1n[e]);
        }
    }
#pragma unroll
    for (int off = 32; off > 0; off >>= 1) {
#pragma unroll
        for (int e = 0; e < EE; ++e) {
            a0r[e] += __shfl_xor(a0r[e], off);
            a0n[e] += __shfl_xor(a0n[e], off);
            a1r[e] += __shfl_xor(a1r[e], off);
            a1n[e] += __shfl_xor(a1n[e], off);
        }
    }

    unsigned e0a, p0a, e1a, p1a, e0b, p0b, e1b, p1b;
    if (lane == 0) {
        route_token(a0r, a0n, t0,     br, bn, noise, e0a, p0a, e1a, p1a);
        route_token(a1r, a1n, t0 + 1, br, bn, noise, e0b, p0b, e1b, p1b);
    }

    __syncthreads();    // all waves done reading WT -> safe to alias
    unsigned* aggp = (unsigned*)WT;        // [32] payloads
    unsigned* agge = aggp + 32;            // [32] expert ids
    if (lane == 0) {
        const int b = wave * 4;
        aggp[b + 0] = p0a; agge[b + 0] = e0a;
        aggp[b + 1] = p1a; agge[b + 1] = e1a;
        aggp[b + 2] = p0b; agge[b + 2] = e0b;
        aggp[b + 3] = p1b; agge[b + 3] = e1b;
    }
    __syncthreads();
    if (tid < EE) {
        int c = 0;
#pragma unroll
        for (int j = 0; j < 32; ++j) c += (agge[j] == (unsigned)tid);
        if (c) {
            int base = atomicAdd(&cnt[tid * 16], c);
            for (int j = 0; j < 32; ++j)
                if (agge[j] == (unsigned)tid) entries[tid * NTOK + (base++)] = aggp[j];
        }
    }
}

// ---------------------------------------------------------------------------
// Grouped GEMM: round-7 measured-best structure (down 103 us):
// 128x128x64 tile, 4 waves (2x2), XOR-swizzled LDS (0 bank conflicts all
// rounds), counted-vmcnt double-buffer, setprio around MFMA, bijective
// chunked XCD swizzle (expert-per-XCD; FETCH ~= compulsory, verified R7).
// Round-8 lesson: 256^2 at 2-phase regressed. Round-10 lesson: fp32
// atomicAdd into out = 222 us (cross-XCD RMW serializes); slots+combine
// restored.
// ---------------------------------------------------------------------------

// Kernel 4: down: hid[off+row][n] = gelu(x_gathered @ WdT^T + bd)
__global__ __launch_bounds__(256) void down_k(
    const ushort* __restrict__ xb, const ushort* __restrict__ WdT, const float* __restrict__ bd,
    const int* __restrict__ cnt, const unsigned* __restrict__ entries, ushort* __restrict__ hid)
{
    const int bx = blockIdx.x;
    const int wid = (bx & 7) * (NWD >> 3) + (bx >> 3);
    const int n0 = (wid % NSL_D) * 128;
    const int tile = wid / NSL_D;
    const int tm = tile % MAXMT;
    const int g = tile / MAXMT, e = g;
    const int n_g = cnt[g * 16];
    if (tm * 128 >= n_g) return;

    int og = 0;
    for (int gg = 0; gg < g; ++gg) og += cnt[gg * 16];   // exclusive prefix

    __shared__ __align__(16) ushort As[2 * 128 * 64];
    __shared__ __align__(16) ushort Bs[2 * 128 * 64];
    __shared__ unsigned ecache[128];

    const int tid = threadIdx.x, lane = tid & 63, w = tid >> 6;
    const int wm = w >> 1, wn = w & 1;
    const int fr = lane & 15, fq = lane >> 4;

    if (tid < 128) {
        const int ridx = min(tm * 128 + tid, n_g - 1);
        ecache[tid] = entries[g * NTOK + ridx];
    }
    __syncthreads();

    const int lr = lane >> 3, seg = lane & 7;
    const int slog = seg ^ lr;                 // row&7 == lr for all j
    const ushort* gA[4]; const ushort* gB[4];
    int loff[4];
    const ushort* WTe = WdT + (size_t)e * HH * DD;
#pragma unroll
    for (int j = 0; j < 4; ++j) {
        const int row = w * 32 + j * 8 + lr;
        const int tok = (int)(ecache[row] & 0x3FFFu);
        gA[j] = xb + (size_t)tok * DD + slog * 8;
        gB[j] = WTe + (size_t)(n0 + row) * DD + slog * 8;
        loff[j] = (w * 256 + j * 64) * 16;     // byte offset within one buffer
    }

    floatx4 acc[4][4];
#pragma unroll
    for (int i = 0; i < 4; ++i)
#pragma unroll
        for (int j = 0; j < 4; ++j) acc[i][j] = (floatx4){0.f, 0.f, 0.f, 0.f};

    const int axr = wm * 64 + fr;
    const int bxr = wn * 64 + fr;

    // prologue: tile 0 -> buf 0 (8 glds per wave in flight)
#pragma unroll
    for (int j = 0; j < 4; ++j) {
        glds16(gA[j], (char*)As + loff[j]);
        glds16(gB[j], (char*)Bs + loff[j]);
    }

    int cur = 0;
    for (int k0 = 0; k0 < DD; k0 += 64) {
        if (k0 + 64 < DD) {
            const int nb = (cur ^ 1) * 16384;
#pragma unroll
            for (int j = 0; j < 4; ++j) {
                glds16(gA[j] + k0 + 64, (char*)As + nb + loff[j]);
                glds16(gB[j] + k0 + 64, (char*)Bs + nb + loff[j]);
            }
            asm volatile("s_waitcnt vmcnt(8)" ::: "memory");  // retire tile-t only
        } else {
            asm volatile("s_waitcnt vmcnt(0)" ::: "memory");  // last tile: drain
        }
        __builtin_amdgcn_sched_barrier(0);
        __builtin_amdgcn_s_barrier();          // all waves: tile-t fully in LDS
        asm volatile("" ::: "memory");
        const int cb = cur * 8192;
        __builtin_amdgcn_s_setprio(1);
#pragma unroll
        for (int kh = 0; kh < 2; ++kh) {
            short8 a[4], b[4];
#pragma unroll
            for (int mt = 0; mt < 4; ++mt) {
                const int r = axr + mt * 16;
                a[mt] = *(const short8*)&As[cb + r * 64 + ((kh * 4 + fq) ^ (r & 7)) * 8];
            }
#pragma unroll
            for (int nt = 0; nt < 4; ++nt) {
                const int r = bxr + nt * 16;
                b[nt] = *(const short8*)&Bs[cb + r * 64 + ((kh * 4 + fq) ^ (r & 7)) * 8];
            }
#pragma unroll
            for (int mt = 0; mt < 4; ++mt)
#pragma unroll
                for (int nt = 0; nt < 4; ++nt)
                    acc[mt][nt] = __builtin_amdgcn_mfma_f32_16x16x32_bf16(a[mt], b[nt], acc[mt][nt], 0, 0, 0);
        }
        __builtin_amdgcn_s_setprio(0);
        asm volatile("" ::: "memory");
        __builtin_amdgcn_s_barrier();          // reads of buf[cur] done before overwrite
        cur ^= 1;
    }

    const int hbase = og + tm * 128;
#pragma unroll
    for (int nt = 0; nt < 4; ++nt) {
        const int n = n0 + wn * 64 + nt * 16 + fr;
        const float bias = bd[e * HH + n];
#pragma unroll
        for (int mt = 0; mt < 4; ++mt)
#pragma unroll
            for (int i = 0; i < 4; ++i) {
                const int rl = wm * 64 + mt * 16 + fq * 4 + i;
                if (tm * 128 + rl < n_g) {
                    const float v = acc[mt][nt][i] + bias;
                    const float ge = 0.5f * v * (1.f + erff(v * 0.7071067811865475f));
                    hid[(size_t)(hbase + rl) * HH + n] = f2bfu(ge);
                }
            }
    }
}

// Kernel 5: up: slots[tok*2+slot][n] = (hid @ WuT^T + bu) * gate (bf16,
// write-only; every slot row written exactly once -> no atomics/RMW).
__global__ __launch_bounds__(256) void up_k(
    const ushort* __restrict__ hid, const ushort* __restrict__ WuT, const float* __restrict__ bu,
    const int* __restrict__ cnt, const unsigned* __restrict__ entries, ushort* __restrict__ slots)
{
    const int bx = blockIdx.x;
    const int wid = (bx & 7) * (NWU >> 3) + (bx >> 3);
    const int n0 = (wid % NSL_U) * 128;
    const int tile = wid / NSL_U;
    const int tm = tile % MAXMT;
    const int g = tile / MAXMT, e = g;
    const int n_g = cnt[g * 16];
    if (tm * 128 >= n_g) return;

    int hbase = 0;
    for (int gg = 0; gg < g; ++gg) hbase += cnt[gg * 16];  // exclusive prefix

    __shared__ __align__(16) ushort As[2 * 128 * 64];
    __shared__ __align__(16) ushort Bs[2 * 128 * 64];
    __shared__ unsigned ecache[128];

    const int tid = threadIdx.x, lane = tid & 63, w = tid >> 6;
    const int wm = w >> 1, wn = w & 1;
    const int fr = lane & 15, fq = lane >> 4;

    if (tid < 128) {
        const int ridx = min(tm * 128 + tid, n_g - 1);
        ecache[tid] = entries[g * NTOK + ridx];
    }
    __syncthreads();

    const int lr = lane >> 3, seg = lane & 7;
    const int slog = seg ^ lr;
    const ushort* gA[4]; const ushort* gB[4];
    int loff[4];
    const ushort* WTe = WuT + (size_t)e * DD * HH;
#pragma unroll
    for (int j = 0; j < 4; ++j) {
        const int row = w * 32 + j * 8 + lr;
        const int ar = min(tm * 128 + row, n_g - 1);
        gA[j] = hid + (size_t)(hbase + ar) * HH + slog * 8;
        gB[j] = WTe + (size_t)(n0 + row) * HH + slog * 8;
        loff[j] = (w * 256 + j * 64) * 16;
    }

    floatx4 acc[4][4];
#pragma unroll
    for (int i = 0; i < 4; ++i)
#pragma unroll
        for (int j = 0; j < 4; ++j) acc[i][j] = (floatx4){0.f, 0.f, 0.f, 0.f};

    const int axr = wm * 64 + fr;
    const int bxr = wn * 64 + fr;

    // prologue: tile 0 -> buf 0
#pragma unroll
    for (int j = 0; j < 4; ++j) {
        glds16(gA[j], (char*)As + loff[j]);
        glds16(gB[j], (char*)Bs + loff[j]);
    }

    int cur = 0;
    for (int k0 = 0; k0 < HH; k0 += 64) {
        if (k0 + 64 < HH) {
            const int nb = (cur ^ 1) * 16384;
#pragma unroll
            for (int j = 0; j < 4; ++j) {
                glds16(gA[j] + k0 + 64, (char*)As + nb + loff[j]);
                glds16(gB[j] + k0 + 64, (char*)Bs + nb + loff[j]);
            }
            asm volatile("s_waitcnt vmcnt(8)" ::: "memory");
        } else {
            asm volatile("s_waitcnt vmcnt(0)" ::: "memory");
        }
        __builtin_amdgcn_sched_barrier(0);
        __builtin_amdgcn_s_barrier();
        asm volatile("" ::: "memory");
        const int cb = cur * 8192;
        __builtin_amdgcn_s_setprio(1);
#pragma unroll
        for (int kh = 0; kh < 2; ++kh) {
            short8 a[4], b[4];
#pragma unroll
            for (int mt = 0; mt < 4; ++mt) {
                const int r = axr + mt * 16;
                a[mt] = *(const short8*)&As[cb + r * 64 + ((kh * 4 + fq) ^ (r & 7)) * 8];
            }
#pragma unroll
            for (int nt = 0; nt < 4; ++nt) {
                const int r = bxr + nt * 16;
                b[nt] = *(const short8*)&Bs[cb + r * 64 + ((kh * 4 + fq) ^ (r & 7)) * 8];
            }
#pragma unroll
            for (int mt = 0; mt < 4; ++mt)
#pragma unroll
                for (int nt = 0; nt < 4; ++nt)
                    acc[mt][nt] = __builtin_amdgcn_mfma_f32_16x16x32_bf16(a[mt], b[nt], acc[mt][nt], 0, 0, 0);
        }
        __builtin_amdgcn_s_setprio(0);
        asm volatile("" ::: "memory");
        __builtin_amdgcn_s_barrier();
        cur ^= 1;
    }

#pragma unroll
    for (int nt = 0; nt < 4; ++nt) {
        const int n = n0 + wn * 64 + nt * 16 + fr;
        const float bias = bu[e * DD + n];
#pragma unroll
        for (int mt = 0; mt < 4; ++mt)
#pragma unroll
            for (int i = 0; i < 4; ++i) {
                const int rl = wm * 64 + mt * 16 + fq * 4 + i;
                if (tm * 128 + rl < n_g) {
                    const unsigned en = ecache[rl];
                    const int tok = (int)(en & 0x3FFFu);
                    const int slot = (int)((en >> 14) & 1u);
                    ushort hb = (ushort)(en >> 16);
                    const float gate = __half2float(*reinterpret_cast<__half*>(&hb));
                    const float v = (acc[mt][nt][i] + bias) * gate;
                    slots[((size_t)tok * 2 + slot) * DD + n] = f2bfu(v);
                }
            }
    }
}

// Kernel 6: out[t][d] = slots[2t][d] + slots[2t+1][d]  (fp32 out, 8 elems/thread)
__global__ __launch_bounds__(256) void combine_k(
    const ushort* __restrict__ slots, float* __restrict__ out)
{
    const size_t flat = ((size_t)blockIdx.x * 256 + threadIdx.x) * 8;
    const size_t t = flat >> 10;         // / DD
    const size_t d = flat & (DD - 1);
    union { uint4 v; ushort h[8]; } a, b;
    a.v = *(const uint4*)(slots + ((t * 2 + 0) << 10) + d);
    b.v = *(const uint4*)(slots + ((t * 2 + 1) << 10) + d);
    float o[8];
#pragma unroll
    for (int j = 0; j < 8; ++j) o[j] = bfu2f(a.h[j]) + bfu2f(b.h[j]);
    *(float4*)(out + flat) = *(const float4*)&o[0];
    *(float4*)(out + flat + 4) = *(const float4*)&o[4];
}

// ---------------------------------------------------------------------------
// Workspace layout (bytes):
//   0         cnt    : int[8] @ 64B stride (256-int region zeroed by trans2_k)
//   2048      entries: u32[8][16384]             (0.5 MB)
//   1050624   xb     : bf16 [16384][1024]        (32 MB)
//   34605056  WdT    : bf16 [8][512 h][1024 d]   (8 MB)
//   42993664  WuT    : bf16 [8][1024 d][512 h]   (8 MB)
//   51382272  hid    : bf16 [32768][512]         (32 MB)
//   84936704  slots  : bf16 [32768][1024]        (64 MB)
// ---------------------------------------------------------------------------
extern "C" void kernel_launch(void* const* d_in, const int* in_sizes, int n_in,
                              void* d_out, int out_size, void* d_ws, size_t ws_size,
                              hipStream_t stream)
{
    const float* x     = (const float*)d_in[0];
    const float* Wr    = (const float*)d_in[1];
    const float* br    = (const float*)d_in[2];
    const float* Wn    = (const float*)d_in[3];
    const float* bn    = (const float*)d_in[4];
    const float* Wd    = (const float*)d_in[5];
    const float* bd    = (const float*)d_in[6];
    const float* Wu    = (const float*)d_in[7];
    const float* bu    = (const float*)d_in[8];
    const float* noise = (const float*)d_in[9];

    char* ws = (char*)d_ws;
    int*      cnt     = (int*)(ws + 0);
    unsigned* entries = (unsigned*)(ws + 2048);
    ushort*   xb      = (ushort*)(ws + 1050624);
    ushort*   WdT     = (ushort*)(ws + 34605056);
    ushort*   WuT     = (ushort*)(ws + 42993664);
    ushort*   hid     = (ushort*)(ws + 51382272);
    ushort*   slots   = (ushort*)(ws + 84936704);

    trans2_k<<<dim3(16, 16, 16), 256, 0, stream>>>(Wd, WdT, Wu, WuT, cnt);
    router_k<<<NTOK / 16, 512, 0, stream>>>(x, Wr, br, Wn, bn, noise, cnt, entries, xb);
    down_k<<<NWD, 256, 0, stream>>>(xb, WdT, bd, cnt, entries, hid);
    up_k<<<NWU, 256, 0, stream>>>(hid, WuT, bu, cnt, entries, slots);
    combine_k<<<(NTOK * DD) / (256 * 8), 256, 0, stream>>>(slots, (float*)d_out);
}

// Round 14
// 429.988 us; speedup vs baseline: 1.2501x; 1.0762x over previous
//
#include <hip/hip_runtime.h>
#include <hip/hip_bf16.h>
#include <hip/hip_fp16.h>
#include <math.h>

// Problem constants
#define DD   1024
#define EE   8
#define HH   512
#define NTOK 16384        // B*T
#define MAXMT 40          // max 128-row tiles per expert (n_e ~ 4096, sigma ~60 -> 5120 >>safe)
#define NSL_D 4           // down: N=512  -> 4 slices of 128
#define NSL_U 8           // up:   N=1024 -> 8 slices of 128
#define NWD  (EE * MAXMT * NSL_D)   // 1280 blocks, %8==0
#define NWU  (EE * MAXMT * NSL_U)   // 2560 blocks, %8==0

typedef __attribute__((ext_vector_type(8))) short short8;   // 8 bf16
typedef __attribute__((ext_vector_type(4))) float floatx4;  // MFMA C/D frag

__device__ __forceinline__ ushort f2bfu(float f) {
    __hip_bfloat16 h = __float2bfloat16(f);   // RNE
    return *reinterpret_cast<ushort*>(&h);
}
__device__ __forceinline__ float bfu2f(ushort u) {
    union { unsigned u; float f; } cv; cv.u = ((unsigned)u) << 16; return cv.f;
}

// async global->LDS, 16B per lane. LDS dest = wave-uniform base + lane*16.
__device__ __forceinline__ void glds16(const void* g, void* l) {
    __builtin_amdgcn_global_load_lds(
        (const __attribute__((address_space(1))) unsigned int*)g,
        (__attribute__((address_space(3))) unsigned int*)l, 16, 0, 0);
}

// ---------------------------------------------------------------------------
// Kernel 1: BOTH weight transposes in one launch (one fewer grid-drain bubble).
// z<8: Wd [D][H] -> WdT [H][D] (expert z); z>=8: Wu [H][D] -> WuT [D][H].
// Block (0,0,0) also zeroes the 256-int counter region.
// ---------------------------------------------------------------------------
__global__ __launch_bounds__(256) void trans2_k(
    const float* __restrict__ Wd, ushort* __restrict__ WdT,
    const float* __restrict__ Wu, ushort* __restrict__ WuT,
    int* __restrict__ cnt)
{
    if (blockIdx.x == 0 && blockIdx.y == 0 && blockIdx.z == 0 && threadIdx.x < 256)
        cnt[threadIdx.x] = 0;
    const int z = blockIdx.z;
    const float* src; ushort* dst; int R, C, e;
    if (z < EE) { src = Wd; dst = WdT; R = DD; C = HH; e = z; }
    else        { src = Wu; dst = WuT; R = HH; C = DD; e = z - EE; }
    if ((int)blockIdx.x >= C / 64 || (int)blockIdx.y >= R / 64) return;
    const int r0 = blockIdx.y * 64, c0 = blockIdx.x * 64;
    __shared__ float t[64][65];
    const int tid = threadIdx.x;
    const int cseg = (tid & 15) * 4, rr = tid >> 4;
#pragma unroll
    for (int j = 0; j < 4; ++j) {
        const int r = rr + j * 16;
        const float4 v = *(const float4*)(src + ((size_t)e * R + r0 + r) * C + c0 + cseg);
        t[r][cseg] = v.x; t[r][cseg+1] = v.y; t[r][cseg+2] = v.z; t[r][cseg+3] = v.w;
    }
    __syncthreads();
    const int rseg = (tid & 15) * 4;
#pragma unroll
    for (int j = 0; j < 4; ++j) {
        const int crow = (tid >> 4) + j * 16;
        ushort o[4];
#pragma unroll
        for (int q = 0; q < 4; ++q) o[q] = f2bfu(t[rseg + q][crow]);
        *(uint2*)(dst + ((size_t)e * C + c0 + crow) * R + r0 + rseg) = *(uint2*)o;
    }
}

// ---------------------------------------------------------------------------
// Kernel 2: router + x->bf16 cvt (round-7 structure — LDS weight stage +
// per-block LDS-aggregated atomics, 1 atomicAdd per expert per block;
// router dropped out of top-5 with this structure).
// entry payload = tok | slot<<14 | gate_f16<<16.
// ---------------------------------------------------------------------------
__device__ __forceinline__ void route_token(
    const float* ar, const float* an, int t,
    const float* __restrict__ br, const float* __restrict__ bn,
    const float* __restrict__ noise,
    unsigned& e0, unsigned& p0, unsigned& e1, unsigned& p1)
{
    float noisy[EE];
#pragma unroll
    for (int e = 0; e < EE; ++e) {
        const float lg = ar[e] + br[e];
        const float nl = an[e] + bn[e];
        const float sp = fmaxf(nl, 0.f) + log1pf(expf(-fabsf(nl)));
        noisy[e] = lg + noise[(size_t)t * EE + e] * sp;
    }
    int i0 = 0;
#pragma unroll
    for (int e = 1; e < EE; ++e) if (noisy[e] > noisy[i0]) i0 = e;
    int i1 = (i0 == 0) ? 1 : 0;
#pragma unroll
    for (int e = 0; e < EE; ++e) if (e != i0 && noisy[e] > noisy[i1]) i1 = e;
    const float ex = expf(noisy[i1] - noisy[i0]);
    const float g0 = 1.f / (1.f + ex);
    const float g1 = ex / (1.f + ex);
    __half h0 = __float2half_rn(g0), h1 = __float2half_rn(g1);
    e0 = (unsigned)i0;
    e1 = (unsigned)i1;
    p0 = (unsigned)t | ((unsigned)*reinterpret_cast<ushort*>(&h0) << 16);
    p1 = (unsigned)t | (1u << 14) | ((unsigned)*reinterpret_cast<ushort*>(&h1) << 16);
}

__global__ __launch_bounds__(512) void router_k(
    const float* __restrict__ x, const float* __restrict__ Wr, const float* __restrict__ br,
    const float* __restrict__ Wn, const float* __restrict__ bn, const float* __restrict__ noise,
    int* __restrict__ cnt, unsigned* __restrict__ entries, ushort* __restrict__ xb)
{
    __shared__ __align__(16) float WT[DD * 20];   // 80 KB; head reused as agg buffer at the tail

    const int tid = threadIdx.x;
    {
        const int d0 = tid * 2;
#pragma unroll
        for (int r = 0; r < 2; ++r) {
            const int d = d0 + r;
            float4 a = *(const float4*)(Wr + (size_t)d * EE);
            float4 b = *(const float4*)(Wr + (size_t)d * EE + 4);
            float4 c = *(const float4*)(Wn + (size_t)d * EE);
            float4 e4 = *(const float4*)(Wn + (size_t)d * EE + 4);
            float* row = &WT[d * 20];
            *(float4*)(row + 0)  = a;
            *(float4*)(row + 4)  = b;
            *(float4*)(row + 8)  = c;
            *(float4*)(row + 12) = e4;
        }
    }
    __syncthreads();

    const int wave = tid >> 6;
    const int lane = tid & 63;
    const int t0 = blockIdx.x * 16 + wave * 2;

    float a0r[EE], a0n[EE], a1r[EE], a1n[EE];
#pragma unroll
    for (int e = 0; e < EE; ++e) { a0r[e] = 0.f; a0n[e] = 0.f; a1r[e] = 0.f; a1n[e] = 0.f; }

    const float* xr0 = x + (size_t)t0 * DD;
    const float* xr1 = xr0 + DD;
    ushort* xb0 = xb + (size_t)t0 * DD;
    ushort* xb1 = xb0 + DD;

#pragma unroll 4
    for (int s = 0; s < DD / 64; ++s) {
        const int d = s * 64 + lane;
        const float x0 = xr0[d];
        const float x1 = xr1[d];
        xb0[d] = f2bfu(x0);
        xb1[d] = f2bfu(x1);
        const float* row = &WT[d * 20];
        const float4 w0 = *(const float4*)(row + 0);
        const float4 w1 = *(const float4*)(row + 4);
        const float4 w2 = *(const float4*)(row + 8);
        const float4 w3 = *(const float4*)(row + 12);
        const float wr[8] = { w0.x, w0.y, w0.z, w0.w, w1.x, w1.y, w1.z, w1.w };
        const float wn[8] = { w2.x, w2.y, w2.z, w2.w, w3.x, w3.y, w3.z, w3.w };
#pragma unroll
        for (int e = 0; e < EE; ++e) {
            a0r[e] = fmaf(x0, wr[e], a0r[e]);
            a0n[e] = fmaf(x0, wn[e], a0n[e]);
            a1r[e] = fmaf(x1, wr[e], a1r[e]);
            a1n[e] = fmaf(x1, wn[e], a1n[e]);
        }
    }
#pragma unroll
    for (int off = 32; off > 0; off >>= 1) {
#pragma unroll
        for (int e = 0; e < EE; ++e) {
            a0r[e] += __shfl_xor(a0r[e], off);
            a0n[e] += __shfl_xor(a0n[e], off);
            a1r[e] += __shfl_xor(a1r[e], off);
            a1n[e] += __shfl_xor(a1n[e], off);
        }
    }

    unsigned e0a, p0a, e1a, p1a, e0b, p0b, e1b, p1b;
    if (lane == 0) {
        route_token(a0r, a0n, t0,     br, bn, noise, e0a, p0a, e1a, p1a);
        route_token(a1r, a1n, t0 + 1, br, bn, noise, e0b, p0b, e1b, p1b);
    }

    __syncthreads();    // all waves done reading WT -> safe to alias
    unsigned* aggp = (unsigned*)WT;        // [32] payloads
    unsigned* agge = aggp + 32;            // [32] expert ids
    if (lane == 0) {
        const int b = wave * 4;
        aggp[b + 0] = p0a; agge[b + 0] = e0a;
        aggp[b + 1] = p1a; agge[b + 1] = e1a;
        aggp[b + 2] = p0b; agge[b + 2] = e0b;
        aggp[b + 3] = p1b; agge[b + 3] = e1b;
    }
    __syncthreads();
    if (tid < EE) {
        int c = 0;
#pragma unroll
        for (int j = 0; j < 32; ++j) c += (agge[j] == (unsigned)tid);
        if (c) {
            int base = atomicAdd(&cnt[tid * 16], c);
            for (int j = 0; j < 32; ++j)
                if (agge[j] == (unsigned)tid) entries[tid * NTOK + (base++)] = aggp[j];
        }
    }
}

// ---------------------------------------------------------------------------
// Grouped GEMM: round-7 measured-best structure (down 103 us on R7's
// container; 137 us on R13's — identical code+counters, DVFS-variance
// suspect): 128x128x64 tile, 4 waves (2x2), XOR-swizzled LDS (0 bank
// conflicts all rounds), counted-vmcnt double-buffer, setprio around MFMA,
// bijective chunked XCD swizzle (expert-per-XCD; FETCH ~= compulsory, R7).
// R8: 256^2 at 2-phase regressed. R10: fp32 atomicAdd epilogue = 222 us.
// ---------------------------------------------------------------------------

// Kernel 4: down: hid[off+row][n] = gelu(x_gathered @ WdT^T + bd)
__global__ __launch_bounds__(256) void down_k(
    const ushort* __restrict__ xb, const ushort* __restrict__ WdT, const float* __restrict__ bd,
    const int* __restrict__ cnt, const unsigned* __restrict__ entries, ushort* __restrict__ hid)
{
    const int bx = blockIdx.x;
    const int wid = (bx & 7) * (NWD >> 3) + (bx >> 3);
    const int n0 = (wid % NSL_D) * 128;
    const int tile = wid / NSL_D;
    const int tm = tile % MAXMT;
    const int g = tile / MAXMT, e = g;
    const int n_g = cnt[g * 16];
    if (tm * 128 >= n_g) return;

    int og = 0;
    for (int gg = 0; gg < g; ++gg) og += cnt[gg * 16];   // exclusive prefix

    __shared__ __align__(16) ushort As[2 * 128 * 64];
    __shared__ __align__(16) ushort Bs[2 * 128 * 64];
    __shared__ unsigned ecache[128];

    const int tid = threadIdx.x, lane = tid & 63, w = tid >> 6;
    const int wm = w >> 1, wn = w & 1;
    const int fr = lane & 15, fq = lane >> 4;

    if (tid < 128) {
        const int ridx = min(tm * 128 + tid, n_g - 1);
        ecache[tid] = entries[g * NTOK + ridx];
    }
    __syncthreads();

    const int lr = lane >> 3, seg = lane & 7;
    const int slog = seg ^ lr;                 // row&7 == lr for all j
    const ushort* gA[4]; const ushort* gB[4];
    int loff[4];
    const ushort* WTe = WdT + (size_t)e * HH * DD;
#pragma unroll
    for (int j = 0; j < 4; ++j) {
        const int row = w * 32 + j * 8 + lr;
        const int tok = (int)(ecache[row] & 0x3FFFu);
        gA[j] = xb + (size_t)tok * DD + slog * 8;
        gB[j] = WTe + (size_t)(n0 + row) * DD + slog * 8;
        loff[j] = (w * 256 + j * 64) * 16;     // byte offset within one buffer
    }

    floatx4 acc[4][4];
#pragma unroll
    for (int i = 0; i < 4; ++i)
#pragma unroll
        for (int j = 0; j < 4; ++j) acc[i][j] = (floatx4){0.f, 0.f, 0.f, 0.f};

    const int axr = wm * 64 + fr;
    const int bxr = wn * 64 + fr;

    // prologue: tile 0 -> buf 0 (8 glds per wave in flight)
#pragma unroll
    for (int j = 0; j < 4; ++j) {
        glds16(gA[j], (char*)As + loff[j]);
        glds16(gB[j], (char*)Bs + loff[j]);
    }

    int cur = 0;
    for (int k0 = 0; k0 < DD; k0 += 64) {
        if (k0 + 64 < DD) {
            const int nb = (cur ^ 1) * 16384;
#pragma unroll
            for (int j = 0; j < 4; ++j) {
                glds16(gA[j] + k0 + 64, (char*)As + nb + loff[j]);
                glds16(gB[j] + k0 + 64, (char*)Bs + nb + loff[j]);
            }
            asm volatile("s_waitcnt vmcnt(8)" ::: "memory");  // retire tile-t only
        } else {
            asm volatile("s_waitcnt vmcnt(0)" ::: "memory");  // last tile: drain
        }
        __builtin_amdgcn_sched_barrier(0);
        __builtin_amdgcn_s_barrier();          // all waves: tile-t fully in LDS
        asm volatile("" ::: "memory");
        const int cb = cur * 8192;
        __builtin_amdgcn_s_setprio(1);
#pragma unroll
        for (int kh = 0; kh < 2; ++kh) {
            short8 a[4], b[4];
#pragma unroll
            for (int mt = 0; mt < 4; ++mt) {
                const int r = axr + mt * 16;
                a[mt] = *(const short8*)&As[cb + r * 64 + ((kh * 4 + fq) ^ (r & 7)) * 8];
            }
#pragma unroll
            for (int nt = 0; nt < 4; ++nt) {
                const int r = bxr + nt * 16;
                b[nt] = *(const short8*)&Bs[cb + r * 64 + ((kh * 4 + fq) ^ (r & 7)) * 8];
            }
#pragma unroll
            for (int mt = 0; mt < 4; ++mt)
#pragma unroll
                for (int nt = 0; nt < 4; ++nt)
                    acc[mt][nt] = __builtin_amdgcn_mfma_f32_16x16x32_bf16(a[mt], b[nt], acc[mt][nt], 0, 0, 0);
        }
        __builtin_amdgcn_s_setprio(0);
        asm volatile("" ::: "memory");
        __builtin_amdgcn_s_barrier();          // reads of buf[cur] done before overwrite
        cur ^= 1;
    }

    const int hbase = og + tm * 128;
#pragma unroll
    for (int nt = 0; nt < 4; ++nt) {
        const int n = n0 + wn * 64 + nt * 16 + fr;
        const float bias = bd[e * HH + n];
#pragma unroll
        for (int mt = 0; mt < 4; ++mt)
#pragma unroll
            for (int i = 0; i < 4; ++i) {
                const int rl = wm * 64 + mt * 16 + fq * 4 + i;
                if (tm * 128 + rl < n_g) {
                    const float v = acc[mt][nt][i] + bias;
                    const float ge = 0.5f * v * (1.f + erff(v * 0.7071067811865475f));
                    hid[(size_t)(hbase + rl) * HH + n] = f2bfu(ge);
                }
            }
    }
}

// Kernel 5: up: slots[tok*2+slot][n] = (hid @ WuT^T + bu) * gate (bf16,
// write-only; every slot row written exactly once -> no atomics/RMW).
__global__ __launch_bounds__(256) void up_k(
    const ushort* __restrict__ hid, const ushort* __restrict__ WuT, const float* __restrict__ bu,
    const int* __restrict__ cnt, const unsigned* __restrict__ entries, ushort* __restrict__ slots)
{
    const int bx = blockIdx.x;
    const int wid = (bx & 7) * (NWU >> 3) + (bx >> 3);
    const int n0 = (wid % NSL_U) * 128;
    const int tile = wid / NSL_U;
    const int tm = tile % MAXMT;
    const int g = tile / MAXMT, e = g;
    const int n_g = cnt[g * 16];
    if (tm * 128 >= n_g) return;

    int hbase = 0;
    for (int gg = 0; gg < g; ++gg) hbase += cnt[gg * 16];  // exclusive prefix

    __shared__ __align__(16) ushort As[2 * 128 * 64];
    __shared__ __align__(16) ushort Bs[2 * 128 * 64];
    __shared__ unsigned ecache[128];

    const int tid = threadIdx.x, lane = tid & 63, w = tid >> 6;
    const int wm = w >> 1, wn = w & 1;
    const int fr = lane & 15, fq = lane >> 4;

    if (tid < 128) {
        const int ridx = min(tm * 128 + tid, n_g - 1);
        ecache[tid] = entries[g * NTOK + ridx];
    }
    __syncthreads();

    const int lr = lane >> 3, seg = lane & 7;
    const int slog = seg ^ lr;
    const ushort* gA[4]; const ushort* gB[4];
    int loff[4];
    const ushort* WTe = WuT + (size_t)e * DD * HH;
#pragma unroll
    for (int j = 0; j < 4; ++j) {
        const int row = w * 32 + j * 8 + lr;
        const int ar = min(tm * 128 + row, n_g - 1);
        gA[j] = hid + (size_t)(hbase + ar) * HH + slog * 8;
        gB[j] = WTe + (size_t)(n0 + row) * HH + slog * 8;
        loff[j] = (w * 256 + j * 64) * 16;
    }

    floatx4 acc[4][4];
#pragma unroll
    for (int i = 0; i < 4; ++i)
#pragma unroll
        for (int j = 0; j < 4; ++j) acc[i][j] = (floatx4){0.f, 0.f, 0.f, 0.f};

    const int axr = wm * 64 + fr;
    const int bxr = wn * 64 + fr;

    // prologue: tile 0 -> buf 0
#pragma unroll
    for (int j = 0; j < 4; ++j) {
        glds16(gA[j], (char*)As + loff[j]);
        glds16(gB[j], (char*)Bs + loff[j]);
    }

    int cur = 0;
    for (int k0 = 0; k0 < HH; k0 += 64) {
        if (k0 + 64 < HH) {
            const int nb = (cur ^ 1) * 16384;
#pragma unroll
            for (int j = 0; j < 4; ++j) {
                glds16(gA[j] + k0 + 64, (char*)As + nb + loff[j]);
                glds16(gB[j] + k0 + 64, (char*)Bs + nb + loff[j]);
            }
            asm volatile("s_waitcnt vmcnt(8)" ::: "memory");
        } else {
            asm volatile("s_waitcnt vmcnt(0)" ::: "memory");
        }
        __builtin_amdgcn_sched_barrier(0);
        __builtin_amdgcn_s_barrier();
        asm volatile("" ::: "memory");
        const int cb = cur * 8192;
        __builtin_amdgcn_s_setprio(1);
#pragma unroll
        for (int kh = 0; kh < 2; ++kh) {
            short8 a[4], b[4];
#pragma unroll
            for (int mt = 0; mt < 4; ++mt) {
                const int r = axr + mt * 16;
                a[mt] = *(const short8*)&As[cb + r * 64 + ((kh * 4 + fq) ^ (r & 7)) * 8];
            }
#pragma unroll
            for (int nt = 0; nt < 4; ++nt) {
                const int r = bxr + nt * 16;
                b[nt] = *(const short8*)&Bs[cb + r * 64 + ((kh * 4 + fq) ^ (r & 7)) * 8];
            }
#pragma unroll
            for (int mt = 0; mt < 4; ++mt)
#pragma unroll
                for (int nt = 0; nt < 4; ++nt)
                    acc[mt][nt] = __builtin_amdgcn_mfma_f32_16x16x32_bf16(a[mt], b[nt], acc[mt][nt], 0, 0, 0);
        }
        __builtin_amdgcn_s_setprio(0);
        asm volatile("" ::: "memory");
        __builtin_amdgcn_s_barrier();
        cur ^= 1;
    }

#pragma unroll
    for (int nt = 0; nt < 4; ++nt) {
        const int n = n0 + wn * 64 + nt * 16 + fr;
        const float bias = bu[e * DD + n];
#pragma unroll
        for (int mt = 0; mt < 4; ++mt)
#pragma unroll
            for (int i = 0; i < 4; ++i) {
                const int rl = wm * 64 + mt * 16 + fq * 4 + i;
                if (tm * 128 + rl < n_g) {
                    const unsigned en = ecache[rl];
                    const int tok = (int)(en & 0x3FFFu);
                    const int slot = (int)((en >> 14) & 1u);
                    ushort hb = (ushort)(en >> 16);
                    const float gate = __half2float(*reinterpret_cast<__half*>(&hb));
                    const float v = (acc[mt][nt][i] + bias) * gate;
                    slots[((size_t)tok * 2 + slot) * DD + n] = f2bfu(v);
                }
            }
    }
}

// Kernel 6: out[t][d] = slots[2t][d] + slots[2t+1][d]  (fp32 out, 8 elems/thread)
__global__ __launch_bounds__(256) void combine_k(
    const ushort* __restrict__ slots, float* __restrict__ out)
{
    const size_t flat = ((size_t)blockIdx.x * 256 + threadIdx.x) * 8;
    const size_t t = flat >> 10;         // / DD
    const size_t d = flat & (DD - 1);
    union { uint4 v; ushort h[8]; } a, b;
    a.v = *(const uint4*)(slots + ((t * 2 + 0) << 10) + d);
    b.v = *(const uint4*)(slots + ((t * 2 + 1) << 10) + d);
    float o[8];
#pragma unroll
    for (int j = 0; j < 8; ++j) o[j] = bfu2f(a.h[j]) + bfu2f(b.h[j]);
    *(float4*)(out + flat) = *(const float4*)&o[0];
    *(float4*)(out + flat + 4) = *(const float4*)&o[4];
}

// ---------------------------------------------------------------------------
// Workspace layout (bytes):
//   0         cnt    : int[8] @ 64B stride (256-int region zeroed by trans2_k)
//   2048      entries: u32[8][16384]             (0.5 MB)
//   1050624   xb     : bf16 [16384][1024]        (32 MB)
//   34605056  WdT    : bf16 [8][512 h][1024 d]   (8 MB)
//   42993664  WuT    : bf16 [8][1024 d][512 h]   (8 MB)
//   51382272  hid    : bf16 [32768][512]         (32 MB)
//   84936704  slots  : bf16 [32768][1024]        (64 MB)
// ---------------------------------------------------------------------------
extern "C" void kernel_launch(void* const* d_in, const int* in_sizes, int n_in,
                              void* d_out, int out_size, void* d_ws, size_t ws_size,
                              hipStream_t stream)
{
    const float* x     = (const float*)d_in[0];
    const float* Wr    = (const float*)d_in[1];
    const float* br    = (const float*)d_in[2];
    const float* Wn    = (const float*)d_in[3];
    const float* bn    = (const float*)d_in[4];
    const float* Wd    = (const float*)d_in[5];
    const float* bd    = (const float*)d_in[6];
    const float* Wu    = (const float*)d_in[7];
    const float* bu    = (const float*)d_in[8];
    const float* noise = (const float*)d_in[9];

    char* ws = (char*)d_ws;
    int*      cnt     = (int*)(ws + 0);
    unsigned* entries = (unsigned*)(ws + 2048);
    ushort*   xb      = (ushort*)(ws + 1050624);
    ushort*   WdT     = (ushort*)(ws + 34605056);
    ushort*   WuT     = (ushort*)(ws + 42993664);
    ushort*   hid     = (ushort*)(ws + 51382272);
    ushort*   slots   = (ushort*)(ws + 84936704);

    trans2_k<<<dim3(16, 16, 16), 256, 0, stream>>>(Wd, WdT, Wu, WuT, cnt);
    router_k<<<NTOK / 16, 512, 0, stream>>>(x, Wr, br, Wn, bn, noise, cnt, entries, xb);
    down_k<<<NWD, 256, 0, stream>>>(xb, WdT, bd, cnt, entries, hid);
    up_k<<<NWU, 256, 0, stream>>>(hid, WuT, bu, cnt, entries, slots);
    combine_k<<<(NTOK * DD) / (256 * 8), 256, 0, stream>>>(slots, (float*)d_out);
}